// Round 8
// baseline (214.083 us; speedup 1.0000x reference)
//
#include <hip/hip_runtime.h>
#include <stdint.h>

// Fused binary conv, round 8: intra-block software pipeline (2 bands/block).
// Band t+1's global loads are issued in 3 batches of 8 uint4 during band t's
// conv chunks (latency hidden under popcount VALU); double-buffered LDS byte
// tile; sign-extract + byte-write right after each chunk; 1 barrier per band.
// The padded byte-matrix IS the tile: u64 read of sm[r][x][0..7] = channel word
// (byte e = channels 8e..8e+7, little-endian == bit i = channel i).
// Weights+bases precomputed once by prepack_kernel (R7, verified).
// sign(x) bit = signbit(x); dot over 64 ch = 64 - 2*popc(a ^ w); zero halo
// (bits 0 = all +1) with pad contribution folded into bases[class][o].

#define NN 32
#define CC 64
#define HH 112
#define WW 112
#define OO 64
#define HW (HH*WW)        // 12544
#define G4 (HW/4)         // 3136 quads per channel plane

#define BAND 4
#define SB 2              // bands per block (pipelined)
#define NSUP (HH/(BAND*SB))   // 14 superbands (8 rows each)
#define GRID (NN*NSUP)        // 448 blocks
#define BLK 448               // 7 waves

#define TROWS 6           // tile rows per band: h-1 .. h+4
#define TCOLS 114         // halo col + 112 + halo col

typedef float f4v __attribute__((ext_vector_type(4)));

// workspace (u64 words): [0,576) wp | [1024,1312) basesg (f32[9][64])

__global__ __launch_bounds__(576)
void prepack_kernel(const float* __restrict__ wgt, uint64_t* __restrict__ wp,
                    float* __restrict__ basesg) {
    __shared__ uint64_t wl[OO * 9];
    const int t = threadIdx.x;                   // 0..575
    {
        const int o = t / 9, k = t - o * 9;
        uint32_t lo = 0, hi = 0;
        #pragma unroll
        for (int i = 0; i < 64; ++i) {
            const uint32_t s = __float_as_uint(wgt[(o * 64 + i) * 9 + k]) >> 31;
            if (i < 32) lo |= s << i;
            else        hi |= s << (i - 32);
        }
        const uint64_t w = ((uint64_t)hi << 32) | lo;
        wl[t] = w;
        wp[t] = w;
    }
    __syncthreads();
    if (t < OO) {
        const int o = t;
        int contrib[9];
        #pragma unroll
        for (int k = 0; k < 9; ++k)
            contrib[k] = 64 - 2 * (int)__popcll(wl[o * 9 + k]);
        #pragma unroll
        for (int ht = 0; ht < 3; ++ht) {
            #pragma unroll
            for (int wt = 0; wt < 3; ++wt) {
                int sum = 0;
                #pragma unroll
                for (int k = 0; k < 9; ++k) {
                    const int kh = k / 3, kw = k - kh * 3;
                    const bool inv = (ht == 0 && kh == 0) || (ht == 2 && kh == 2) ||
                                     (wt == 0 && kw == 0) || (wt == 2 && kw == 2);
                    if (inv) sum += contrib[k];
                }
                basesg[(ht * 3 + wt) * OO + o] = (float)(576 - sum);
            }
        }
    }
}

__global__ __launch_bounds__(BLK, 3)
void fused_kernel(const float* __restrict__ act, const uint64_t* __restrict__ wp,
                  const float* __restrict__ basesg, float* __restrict__ out) {
    __shared__ uint8_t  sm[2][TROWS][TCOLS][8];  // 10944 B double-buffered tile
    __shared__ uint64_t wlds[OO * 9];            // 4608 B
    __shared__ float    basesl[9 * OO];          // 2304 B

    const int b = blockIdx.x;
    const int n = b / NSUP;
    const int s = b - n * NSUP;                  // superband: rows 8s..8s+7
    const int tid = threadIdx.x;

    // ---- copy precomputed tables (L2-resident ~7KB) ----
    for (int t2 = tid; t2 < OO * 9; t2 += BLK) {
        wlds[t2] = wp[t2];
        basesl[t2] = basesg[t2];
    }

    // ---- zero halo cols of BOTH buffers (never overwritten by pack) ----
    if (tid < 24) {
        const int buf = tid / 12, rr = (tid % 12) >> 1, c = (tid & 1) ? 113 : 0;
        *(uint64_t*)&sm[buf][rr][c][0] = 0ull;
    }

    // ---- prologue: pack band 0 (rows 8s-1..8s+4) into buffer 0 ----
    #pragma unroll
    for (int it = 0; it < 3; ++it) {
        const int item = tid + it * BLK;         // 0..1343 = 6 rows x 8 e x 28 q
        const int pr = item / 224;
        const int rem = item - pr * 224;
        const int pe = rem / 28;
        const int pq = rem - pe * 28;
        const int h = s * 8 - 1 + pr;
        uint32_t b0 = 0, b1 = 0, b2 = 0, b3 = 0;
        if ((unsigned)h < (unsigned)HH) {
            const uint4* bp = (const uint4*)act + ((size_t)n * CC + pe * 8) * G4
                            + (size_t)h * 28 + pq;
            #pragma unroll
            for (int j = 0; j < 8; ++j) {
                const uint4 v = bp[(size_t)j * G4];
                b0 |= (v.x >> 31) << j; b1 |= (v.y >> 31) << j;
                b2 |= (v.z >> 31) << j; b3 |= (v.w >> 31) << j;
            }
        }
        sm[0][pr][4 * pq + 1][pe] = (uint8_t)b0;
        sm[0][pr][4 * pq + 2][pe] = (uint8_t)b1;
        sm[0][pr][4 * pq + 3][pe] = (uint8_t)b2;
        sm[0][pr][4 * pq + 4][pe] = (uint8_t)b3;
    }
    __syncthreads();

    // ---- conv thread mapping (fixed across bands) ----
    const int og = tid / 112;                    // 0..3 -> o in [16og, 16og+16)
    const int qq = tid - og * 112;
    const int cr = qq / 28;                      // 0..3 row within band
    const int qc = qq - cr * 28;                 // 0..27 quad
    const int w0 = 4 * qc;
    const int o0 = og * 16;

    #pragma unroll
    for (int t = 0; t < SB; ++t) {
        const int cur = t & 1;
        const int h = s * 8 + t * 4 + cr;

        // A taps: tile rows cr..cr+2, tile cols w0..w0+5 (= image cols w0-1..w0+4)
        uint64_t A[3][6];
        #pragma unroll
        for (int rr = 0; rr < 3; ++rr)
            #pragma unroll
            for (int j = 0; j < 6; ++j)
                A[rr][j] = *(const uint64_t*)&sm[cur][cr + rr][w0 + j][0];

        const int ht = (h == 0) ? 0 : ((h == HH - 1) ? 2 : 1);
        const float* bp0  = &basesl[(ht * 3 + ((w0 == 0) ? 0 : 1)) * OO];
        const float* bp12 = &basesl[(ht * 3 + 1) * OO];
        const float* bp3  = &basesl[(ht * 3 + ((w0 + 3 == WW - 1) ? 2 : 1)) * OO];
        float* op = out + (size_t)n * (OO * HW) + (size_t)h * WW + w0;

        const bool pf = (t + 1 < SB);

        #pragma unroll
        for (int it = 0; it < 3; ++it) {
            // -- issue prefetch batch `it` for band t+1 (8 independent 16B loads) --
            uint4 v0, v1, v2, v3, v4, v5, v6, v7;
            int pr = 0, pe = 0, pq = 0;
            bool hv = false;
            if (pf) {
                const int item = tid + it * BLK;
                pr = item / 224;
                const int rem = item - pr * 224;
                pe = rem / 28;
                pq = rem - pe * 28;
                const int hp = s * 8 + (t + 1) * 4 - 1 + pr;
                hv = ((unsigned)hp < (unsigned)HH);
                if (hv) {
                    const uint4* bp = (const uint4*)act
                                    + ((size_t)n * CC + pe * 8) * G4
                                    + (size_t)hp * 28 + pq;
                    v0 = bp[0 * (size_t)G4]; v1 = bp[1 * (size_t)G4];
                    v2 = bp[2 * (size_t)G4]; v3 = bp[3 * (size_t)G4];
                    v4 = bp[4 * (size_t)G4]; v5 = bp[5 * (size_t)G4];
                    v6 = bp[6 * (size_t)G4]; v7 = bp[7 * (size_t)G4];
                }
            }

            // -- conv chunk: o sub-range {6,5,5} of this thread's 16 o --
            const int oA = o0 + ((it == 0) ? 0 : (it == 1) ? 6 : 11);
            const int oB = o0 + ((it == 0) ? 6 : (it == 1) ? 11 : 16);
            for (int o = oA; o < oB; ++o) {
                const uint64_t* wk = &wlds[o * 9];
                int s0 = 0, s1 = 0, s2 = 0, s3 = 0;
                #pragma unroll
                for (int kh = 0; kh < 3; ++kh) {
                    #pragma unroll
                    for (int kw = 0; kw < 3; ++kw) {
                        const uint64_t wv = wk[kh * 3 + kw];
                        s0 += __popcll(A[kh][kw    ] ^ wv);
                        s1 += __popcll(A[kh][kw + 1] ^ wv);
                        s2 += __popcll(A[kh][kw + 2] ^ wv);
                        s3 += __popcll(A[kh][kw + 3] ^ wv);
                    }
                }
                f4v r;
                r.x = bp0[o]  - 2.0f * (float)s0;
                r.y = bp12[o] - 2.0f * (float)s1;
                r.z = bp12[o] - 2.0f * (float)s2;
                r.w = bp3[o]  - 2.0f * (float)s3;
                __builtin_nontemporal_store(r, (f4v*)(op + (size_t)o * HW));
            }

            // -- drain batch: extract signs, byte-write into the other buffer --
            if (pf) {
                uint32_t b0 = 0, b1 = 0, b2 = 0, b3 = 0;
                if (hv) {
                    b0 = (v0.x >> 31) | ((v1.x >> 31) << 1) | ((v2.x >> 31) << 2)
                       | ((v3.x >> 31) << 3) | ((v4.x >> 31) << 4)
                       | ((v5.x >> 31) << 5) | ((v6.x >> 31) << 6) | ((v7.x >> 31) << 7);
                    b1 = (v0.y >> 31) | ((v1.y >> 31) << 1) | ((v2.y >> 31) << 2)
                       | ((v3.y >> 31) << 3) | ((v4.y >> 31) << 4)
                       | ((v5.y >> 31) << 5) | ((v6.y >> 31) << 6) | ((v7.y >> 31) << 7);
                    b2 = (v0.z >> 31) | ((v1.z >> 31) << 1) | ((v2.z >> 31) << 2)
                       | ((v3.z >> 31) << 3) | ((v4.z >> 31) << 4)
                       | ((v5.z >> 31) << 5) | ((v6.z >> 31) << 6) | ((v7.z >> 31) << 7);
                    b3 = (v0.w >> 31) | ((v1.w >> 31) << 1) | ((v2.w >> 31) << 2)
                       | ((v3.w >> 31) << 3) | ((v4.w >> 31) << 4)
                       | ((v5.w >> 31) << 5) | ((v6.w >> 31) << 6) | ((v7.w >> 31) << 7);
                }
                const int nb = cur ^ 1;
                sm[nb][pr][4 * pq + 1][pe] = (uint8_t)b0;
                sm[nb][pr][4 * pq + 2][pe] = (uint8_t)b1;
                sm[nb][pr][4 * pq + 3][pe] = (uint8_t)b2;
                sm[nb][pr][4 * pq + 4][pe] = (uint8_t)b3;
            }
        }
        __syncthreads();
    }
}

extern "C" void kernel_launch(void* const* d_in, const int* in_sizes, int n_in,
                              void* d_out, int out_size, void* d_ws, size_t ws_size,
                              hipStream_t stream) {
    const float* act = (const float*)d_in[0];
    const float* wgt = (const float*)d_in[1];
    float* out = (float*)d_out;

    uint64_t* wp = (uint64_t*)d_ws;              // 576 u64
    float* basesg = (float*)(wp + 1024);         // 576 f32

    prepack_kernel<<<1, 576, 0, stream>>>(wgt, wp, basesg);
    fused_kernel<<<GRID, BLK, 0, stream>>>(act, wp, basesg, out);
}